// Round 1
// baseline (567.337 us; speedup 1.0000x reference)
//
#include <hip/hip_runtime.h>
#include <hip/hip_bf16.h>
#include <stdint.h>

// ---------------------------------------------------------------------------
// LinearQuantizer: y = fakequant_i8(x, per-tensor) @ fakequant_i8(W, per-row)^T + b
// Strategy: exact int8 GEMM via v_mfma_i32_16x16x64_i8, scales applied in epilogue.
// ---------------------------------------------------------------------------

#define QMAX_F 127.0f
#define EPS_F 1e-8f

typedef int v4i __attribute__((ext_vector_type(4)));

// ---- workspace layout ----
// [0..4)        : uint32 absmax bits of |x| (atomicMax target)
// [64..16448)   : w_scale[4096] f32 (eps-clamped)
// [XQ_OFF ...)  : xq int8 [M][K]
// [WQ_OFF ...)  : wq int8 [N][K]
static constexpr size_t WSCALE_OFF = 64;
static constexpr size_t XQ_OFF = 1u << 16;

// ---------------- absmax over x (exact, order-independent) ----------------
__global__ void absmax_kernel(const float4* __restrict__ x, unsigned* __restrict__ out, int n4) {
    int tid = blockIdx.x * blockDim.x + threadIdx.x;
    int stride = gridDim.x * blockDim.x;
    float m = 0.0f;
    for (int i = tid; i < n4; i += stride) {
        float4 v = x[i];
        m = fmaxf(m, fmaxf(fmaxf(fabsf(v.x), fabsf(v.y)), fmaxf(fabsf(v.z), fabsf(v.w))));
    }
    for (int off = 32; off > 0; off >>= 1)
        m = fmaxf(m, __shfl_xor(m, off));
    __shared__ float wmax[4];
    int lane = threadIdx.x & 63, wid = threadIdx.x >> 6;
    if (lane == 0) wmax[wid] = m;
    __syncthreads();
    if (threadIdx.x == 0) {
        float b = fmaxf(fmaxf(wmax[0], wmax[1]), fmaxf(wmax[2], wmax[3]));
        atomicMax(out, __float_as_uint(b));  // |x| >= 0 -> uint order == float order
    }
}

__device__ __forceinline__ int quant1(float v, float s) {
    float t = v / s;
    t = fminf(fmaxf(t, -QMAX_F), QMAX_F);  // clip then round, matches reference
    return (int)rintf(t);                  // round-half-even == jnp.round
}

// ---------------- quantize x -> int8 (packed 4/int) ----------------
__global__ void quantx_kernel(const float4* __restrict__ x, const unsigned* __restrict__ amax,
                              int* __restrict__ xq, int n4) {
    float s = fmaxf(__uint_as_float(*amax) / QMAX_F, EPS_F);
    int tid = blockIdx.x * blockDim.x + threadIdx.x;
    int stride = gridDim.x * blockDim.x;
    for (int i = tid; i < n4; i += stride) {
        float4 v = x[i];
        int q0 = quant1(v.x, s), q1 = quant1(v.y, s), q2 = quant1(v.z, s), q3 = quant1(v.w, s);
        xq[i] = (q0 & 0xff) | ((q1 & 0xff) << 8) | ((q2 & 0xff) << 16) | ((q3 & 0xff) << 24);
    }
}

// ---------------- quantize W per-row -> int8 + w_scale ----------------
__global__ void quantw_kernel(const float4* __restrict__ w, int* __restrict__ wq,
                              float* __restrict__ w_scale, int K4 /* = K/4 = 1024 */) {
    int row = blockIdx.x;
    const float4* wr = w + (size_t)row * K4;
    int t = threadIdx.x;  // 256
    float4 vals[4];
    float m = 0.0f;
    for (int i = 0; i < 4; i++) {
        float4 v = wr[t + 256 * i];
        vals[i] = v;
        m = fmaxf(m, fmaxf(fmaxf(fabsf(v.x), fabsf(v.y)), fmaxf(fabsf(v.z), fabsf(v.w))));
    }
    for (int off = 32; off > 0; off >>= 1)
        m = fmaxf(m, __shfl_xor(m, off));
    __shared__ float sm[4];
    if ((t & 63) == 0) sm[t >> 6] = m;
    __syncthreads();
    float mb = fmaxf(fmaxf(sm[0], sm[1]), fmaxf(sm[2], sm[3]));
    float s = fmaxf(mb / QMAX_F, EPS_F);
    if (t == 0) w_scale[row] = s;
    int* wqr = wq + (size_t)row * K4;
    for (int i = 0; i < 4; i++) {
        float4 v = vals[i];
        int q0 = quant1(v.x, s), q1 = quant1(v.y, s), q2 = quant1(v.z, s), q3 = quant1(v.w, s);
        wqr[t + 256 * i] = (q0 & 0xff) | ((q1 & 0xff) << 8) | ((q2 & 0xff) << 16) | ((q3 & 0xff) << 24);
    }
}

// ---------------- int8 GEMM: C[M][N] = Xq[M][K] * Wq[N][K]^T ----------------
// 128x128 tile, BK=64, 256 threads / 4 waves (2x2), wave = 64x64 = 4x4 frags
// of mfma_i32_16x16x64_i8. m97-structure: global_load_lds(16B) staging,
// 2-barrier K-loop, XCD-aware block swizzle.
#define BM 128
#define BN 128
#define BK 64

__device__ __forceinline__ void gload_lds16(const char* g, char* l) {
    __builtin_amdgcn_global_load_lds(
        (const __attribute__((address_space(1))) void*)g,
        (__attribute__((address_space(3))) void*)l, 16, 0, 0);
}

__global__ __launch_bounds__(256) void gemm_i8_kernel(
    const char* __restrict__ xq, const char* __restrict__ wq,
    const float* __restrict__ w_scale, const unsigned* __restrict__ amax,
    const float* __restrict__ bias, float* __restrict__ out,
    int M, int N, int K) {
    __shared__ __align__(16) char As[BM * BK];  // 8 KB
    __shared__ __align__(16) char Bs[BN * BK];  // 8 KB

    // XCD-aware swizzle: grid = nbm*nbn = 4096, divisible by 8 -> bijective
    int nwg = gridDim.x;
    int bid = blockIdx.x;
    int cpx = nwg >> 3;
    int swz = (bid & 7) * cpx + (bid >> 3);
    int nbm = M / BM;
    int bm = swz % nbm;
    int bn = swz / nbm;

    int t = threadIdx.x;
    int lane = t & 63;
    int wid = t >> 6;
    int wr = wid >> 1, wc = wid & 1;  // 2x2 wave grid, each wave 64x64 out

    // staging addresses: thread t loads 16B, row = t>>2 (64 rows/issue), col16 = t&3
    const char* aG = xq + (size_t)(bm * BM + (t >> 2)) * K + (t & 3) * 16;
    const char* bG = wq + (size_t)(bn * BN + (t >> 2)) * K + (t & 3) * 16;
    char* aL0 = As + t * 16;
    char* aL1 = As + 4096 + t * 16;
    char* bL0 = Bs + t * 16;
    char* bL1 = Bs + 4096 + t * 16;
    const size_t rowStride64 = (size_t)64 * K;

    v4i acc[4][4];
#pragma unroll
    for (int m = 0; m < 4; m++)
#pragma unroll
        for (int n = 0; n < 4; n++) acc[m][n] = (v4i){0, 0, 0, 0};

    const v4i* Asv = (const v4i*)As;
    const v4i* Bsv = (const v4i*)Bs;
    int rofs = lane & 15;        // row within 16x16 frag
    int kslot = lane >> 4;       // which 16B K-slot (0..3 over BK=64)

    for (int kt = 0; kt < K; kt += BK) {
        gload_lds16(aG + kt, aL0);
        gload_lds16(aG + kt + rowStride64, aL1);
        gload_lds16(bG + kt, bL0);
        gload_lds16(bG + kt + rowStride64, bL1);
        __syncthreads();  // compiler emits vmcnt(0) drain before barrier

        v4i a[4], b[4];
#pragma unroll
        for (int m = 0; m < 4; m++)
            a[m] = Asv[(wr * 64 + m * 16 + rofs) * 4 + kslot];
#pragma unroll
        for (int n = 0; n < 4; n++)
            b[n] = Bsv[(wc * 64 + n * 16 + rofs) * 4 + kslot];
#pragma unroll
        for (int m = 0; m < 4; m++)
#pragma unroll
            for (int n = 0; n < 4; n++)
                acc[m][n] = __builtin_amdgcn_mfma_i32_16x16x64_i8(a[m], b[n], acc[m][n], 0, 0, 0);
        __syncthreads();  // all reads done before next staging overwrites
    }

    // epilogue: y = acc * (a_scale * w_scale[col]) + bias[col]
    float a_s = fmaxf(__uint_as_float(*amax) / QMAX_F, EPS_F);
    int row0 = bm * BM + wr * 64;
    int col0 = bn * BN + wc * 64;
#pragma unroll
    for (int n = 0; n < 4; n++) {
        int col = col0 + n * 16 + (lane & 15);
        float f = a_s * w_scale[col];
        float bv = bias[col];
#pragma unroll
        for (int m = 0; m < 4; m++) {
            int row = row0 + m * 16 + (lane >> 4) * 4;
#pragma unroll
            for (int j = 0; j < 4; j++) {
                out[(size_t)(row + j) * N + col] = (float)acc[m][n][j] * f + bv;
            }
        }
    }
}

extern "C" void kernel_launch(void* const* d_in, const int* in_sizes, int n_in,
                              void* d_out, int out_size, void* d_ws, size_t ws_size,
                              hipStream_t stream) {
    const float* x = (const float*)d_in[0];
    const float* w = (const float*)d_in[1];
    const float* bias = (const float*)d_in[2];
    float* out = (float*)d_out;

    const int N = in_sizes[2];                 // 4096 (D_OUT)
    const int K = in_sizes[1] / N;             // 4096 (D_IN)
    const int M = in_sizes[0] / K;             // 16384 (B*S)

    char* ws = (char*)d_ws;
    unsigned* amax = (unsigned*)ws;
    float* w_scale = (float*)(ws + WSCALE_OFF);
    char* xq = ws + XQ_OFF;
    char* wq = ws + XQ_OFF + (size_t)M * K;

    size_t needed = XQ_OFF + (size_t)M * K + (size_t)N * K;
    if (ws_size < needed) return;  // workspace too small (shouldn't happen)

    hipMemsetAsync(amax, 0, 4, stream);  // poison is 0xAA... (huge uint) -> must zero

    int n4x = (M * K) / 4;
    absmax_kernel<<<2048, 256, 0, stream>>>((const float4*)x, amax, n4x);
    quantx_kernel<<<2048, 256, 0, stream>>>((const float4*)x, amax, (int*)xq, n4x);
    quantw_kernel<<<N, 256, 0, stream>>>((const float4*)w, (int*)wq, w_scale, K / 4);

    int grid = (M / BM) * (N / BN);  // 128*32 = 4096
    gemm_i8_kernel<<<grid, 256, 0, stream>>>(xq, wq, w_scale, amax, bias, out, M, N, K);
}

// Round 2
// 445.720 us; speedup vs baseline: 1.2729x; 1.2729x over previous
//
#include <hip/hip_runtime.h>
#include <hip/hip_bf16.h>
#include <stdint.h>

// ---------------------------------------------------------------------------
// LinearQuantizer: y = fakequant_i8(x, per-tensor) @ fakequant_i8(W, per-row)^T + b
// int8 GEMM via v_mfma_i32_16x16x64_i8, 256x256 tile, 8-phase counted-vmcnt
// schedule (T2 swizzle + T3/T4 + T5), scales applied in epilogue.
// ---------------------------------------------------------------------------

#define QMAX_F 127.0f
#define EPS_F 1e-8f

typedef int v4i __attribute__((ext_vector_type(4)));

static constexpr size_t WSCALE_OFF = 64;
static constexpr size_t XQ_OFF = 1u << 16;

// ---------------- absmax over x (exact, order-independent) ----------------
__global__ void absmax_kernel(const float4* __restrict__ x, unsigned* __restrict__ out, int n4) {
    int tid = blockIdx.x * blockDim.x + threadIdx.x;
    int stride = gridDim.x * blockDim.x;
    float m = 0.0f;
    for (int i = tid; i < n4; i += stride) {
        float4 v = x[i];
        m = fmaxf(m, fmaxf(fmaxf(fabsf(v.x), fabsf(v.y)), fmaxf(fabsf(v.z), fabsf(v.w))));
    }
    for (int off = 32; off > 0; off >>= 1)
        m = fmaxf(m, __shfl_xor(m, off));
    __shared__ float wmax[4];
    int lane = threadIdx.x & 63, wid = threadIdx.x >> 6;
    if (lane == 0) wmax[wid] = m;
    __syncthreads();
    if (threadIdx.x == 0) {
        float b = fmaxf(fmaxf(wmax[0], wmax[1]), fmaxf(wmax[2], wmax[3]));
        atomicMax(out, __float_as_uint(b));
    }
}

__device__ __forceinline__ int quant1(float v, float s) {
    float t = v / s;
    t = fminf(fmaxf(t, -QMAX_F), QMAX_F);
    return (int)rintf(t);
}

// ---------------- quantize x -> int8 ----------------
__global__ void quantx_kernel(const float4* __restrict__ x, const unsigned* __restrict__ amax,
                              int* __restrict__ xq, int n4) {
    float s = fmaxf(__uint_as_float(*amax) / QMAX_F, EPS_F);
    int tid = blockIdx.x * blockDim.x + threadIdx.x;
    int stride = gridDim.x * blockDim.x;
    for (int i = tid; i < n4; i += stride) {
        float4 v = x[i];
        int q0 = quant1(v.x, s), q1 = quant1(v.y, s), q2 = quant1(v.z, s), q3 = quant1(v.w, s);
        xq[i] = (q0 & 0xff) | ((q1 & 0xff) << 8) | ((q2 & 0xff) << 16) | ((q3 & 0xff) << 24);
    }
}

// ---------------- quantize W per-row -> int8 + w_scale ----------------
__global__ void quantw_kernel(const float4* __restrict__ w, int* __restrict__ wq,
                              float* __restrict__ w_scale, int K4) {
    int row = blockIdx.x;
    const float4* wr = w + (size_t)row * K4;
    int t = threadIdx.x;  // 256
    float4 vals[4];
    float m = 0.0f;
    for (int i = 0; i < 4; i++) {
        float4 v = wr[t + 256 * i];
        vals[i] = v;
        m = fmaxf(m, fmaxf(fmaxf(fabsf(v.x), fabsf(v.y)), fmaxf(fabsf(v.z), fabsf(v.w))));
    }
    for (int off = 32; off > 0; off >>= 1)
        m = fmaxf(m, __shfl_xor(m, off));
    __shared__ float sm[4];
    if ((t & 63) == 0) sm[t >> 6] = m;
    __syncthreads();
    float mb = fmaxf(fmaxf(sm[0], sm[1]), fmaxf(sm[2], sm[3]));
    float s = fmaxf(mb / QMAX_F, EPS_F);
    if (t == 0) w_scale[row] = s;
    int* wqr = wq + (size_t)row * K4;
    for (int i = 0; i < 4; i++) {
        float4 v = vals[i];
        int q0 = quant1(v.x, s), q1 = quant1(v.y, s), q2 = quant1(v.z, s), q3 = quant1(v.w, s);
        wqr[t + 256 * i] = (q0 & 0xff) | ((q1 & 0xff) << 8) | ((q2 & 0xff) << 16) | ((q3 & 0xff) << 24);
    }
}

// ---------------- int8 GEMM, 256x256 tile, 8-phase schedule ----------------
#define BM 256
#define BN 256
#define BKB 128  // K-bytes (=elements) per K-tile

__device__ __forceinline__ void gload16(const char* g, char* l) {
    __builtin_amdgcn_global_load_lds(
        (const __attribute__((address_space(1))) void*)g,
        (__attribute__((address_space(3))) void*)l, 16, 0, 0);
}

__global__ __launch_bounds__(512, 2) void gemm_i8_8ph(
    const char* __restrict__ xq, const char* __restrict__ wq,
    const float* __restrict__ w_scale, const unsigned* __restrict__ amax,
    const float* __restrict__ bias, float* __restrict__ out,
    int M, int N, int K) {
    // LDS: [buf 2][op 2 (A,B)][half 2][row 128][col 128B] = 128 KiB
    __shared__ __align__(16) char lds[131072];

    // XCD-aware bijective swizzle (nwg = 1024, % 8 == 0)
    const int nwg = gridDim.x, bid = blockIdx.x;
    const int cpx = nwg >> 3;
    const int swz = (bid & 7) * cpx + (bid >> 3);
    const int nbm = M / BM;
    const int bm = swz % nbm, bn = swz / nbm;

    const int t = threadIdx.x;
    const int lane = t & 63, wid = t >> 6;
    const int wr = wid >> 2, wc = wid & 3;  // 2 (M) x 4 (N) waves; wave out = 128x64

    // ---- staging: linear LDS dest (t*16), pre-swizzled global source col ----
    const int srow = t >> 3;                          // row within 64-row chunk
    const int scol = ((t & 7) ^ (srow & 7)) << 4;     // inverse-swizzled source col
    const char* aSrc = xq + (size_t)(bm * BM + srow) * K + scol;
    const char* bSrc = wq + (size_t)(bn * BN + srow) * K + scol;
    char* ldsT = lds + t * 16;

    auto stageA = [&](int half, int tt, int ktc) {
        char* d = ldsT + ((unsigned)(tt & 1) << 16) + ((unsigned)half << 14);
        gload16(aSrc + (size_t)(half * 128) * K + ktc, d);
        gload16(aSrc + (size_t)(half * 128 + 64) * K + ktc, d + 8192);
    };
    auto stageB = [&](int half, int tt, int ktc) {
        char* d = ldsT + ((unsigned)(tt & 1) << 16) + 32768u + ((unsigned)half << 14);
        gload16(bSrc + (size_t)(half * 128) * K + ktc, d);
        gload16(bSrc + (size_t)(half * 128 + 64) * K + ktc, d + 8192);
    };

    // ---- ds_read addressing (swizzled col: byte ^= ((row&7)<<4)) ----
    const int rA = lane & 15, kg = lane >> 4, sw7 = lane & 7;
    const unsigned cks0 = (unsigned)((kg ^ sw7) << 4);
    const unsigned cks1 = (unsigned)(((4 + kg) ^ sw7) << 4);
    // A frag (mh,m,ks): bb + wr*16384 + mh*8192 + m*2048 + rA*128 + cks
    const unsigned aBase = ((unsigned)wr << 14) + ((unsigned)rA << 7);
    // B frag (nh,n,ks): bb + 32768 + wc*8192 + nh*4096 + n*2048 + rA*128 + cks
    const unsigned bBase = 32768u + ((unsigned)wc << 13) + ((unsigned)rA << 7);

    v4i acc[8][4];
#pragma unroll
    for (int m = 0; m < 8; m++)
#pragma unroll
        for (int n = 0; n < 4; n++) acc[m][n] = (v4i){0, 0, 0, 0};

    const int nkt = K / BKB;  // 32

    // ---- prologue: tile0 fully + 3 half-tiles of tile1 ----
    stageA(0, 0, 0); stageA(1, 0, 0); stageB(0, 0, 0); stageB(1, 0, 0);
    {
        const int k1 = (1 < nkt) ? BKB : 0;
        stageB(0, 1, k1); stageA(0, 1, k1); stageB(1, 1, k1);
    }
    asm volatile("s_waitcnt vmcnt(6)" ::: "memory");  // tile0's 8 loads retired
    __builtin_amdgcn_s_barrier();

    for (int T = 0; T < nkt; ++T) {
        const unsigned bb = (unsigned)(T & 1) << 16;
        const int kA1 = (T + 1 < nkt) ? (T + 1) * BKB : 0;  // clamped: loads always issue
        const int kT2 = (T + 2 < nkt) ? (T + 2) * BKB : 0;
        v4i a[4][2], b0[2][2], b1[2][2];

        // ===== ph1: read A-mh0 (8) + B-nh0 (4); stage A-h1(T+1); MFMA q(0,0) =====
#pragma unroll
        for (int m = 0; m < 4; m++) {
            a[m][0] = *(const v4i*)(lds + bb + aBase + ((unsigned)m << 11) + cks0);
            a[m][1] = *(const v4i*)(lds + bb + aBase + ((unsigned)m << 11) + cks1);
        }
#pragma unroll
        for (int n = 0; n < 2; n++) {
            b0[n][0] = *(const v4i*)(lds + bb + bBase + ((unsigned)n << 11) + cks0);
            b0[n][1] = *(const v4i*)(lds + bb + bBase + ((unsigned)n << 11) + cks1);
        }
        stageA(1, T + 1, kA1);
        __builtin_amdgcn_s_barrier();
        asm volatile("s_waitcnt lgkmcnt(0)" ::: "memory");
        __builtin_amdgcn_sched_barrier(0);
        __builtin_amdgcn_s_setprio(1);
#pragma unroll
        for (int ks = 0; ks < 2; ks++)
#pragma unroll
            for (int m = 0; m < 4; m++)
#pragma unroll
                for (int n = 0; n < 2; n++)
                    acc[m][n] = __builtin_amdgcn_mfma_i32_16x16x64_i8(a[m][ks], b0[n][ks], acc[m][n], 0, 0, 0);
        __builtin_amdgcn_s_setprio(0);
        __builtin_amdgcn_s_barrier();

        // ===== ph2: read B-nh1 (4); MFMA q(0,1) =====
#pragma unroll
        for (int n = 0; n < 2; n++) {
            b1[n][0] = *(const v4i*)(lds + bb + bBase + 4096u + ((unsigned)n << 11) + cks0);
            b1[n][1] = *(const v4i*)(lds + bb + bBase + 4096u + ((unsigned)n << 11) + cks1);
        }
        __builtin_amdgcn_s_barrier();
        asm volatile("s_waitcnt lgkmcnt(0)" ::: "memory");
        __builtin_amdgcn_sched_barrier(0);
        __builtin_amdgcn_s_setprio(1);
#pragma unroll
        for (int ks = 0; ks < 2; ks++)
#pragma unroll
            for (int m = 0; m < 4; m++)
#pragma unroll
                for (int n = 0; n < 2; n++)
                    acc[m][2 + n] = __builtin_amdgcn_mfma_i32_16x16x64_i8(a[m][ks], b1[n][ks], acc[m][2 + n], 0, 0, 0);
        __builtin_amdgcn_s_setprio(0);
        __builtin_amdgcn_s_barrier();

        // ===== ph3: read A-mh1 (8); stage B-h0(T+2); MFMA q(1,1) =====
#pragma unroll
        for (int m = 0; m < 4; m++) {
            a[m][0] = *(const v4i*)(lds + bb + aBase + 8192u + ((unsigned)m << 11) + cks0);
            a[m][1] = *(const v4i*)(lds + bb + aBase + 8192u + ((unsigned)m << 11) + cks1);
        }
        stageB(0, T + 2, kT2);
        __builtin_amdgcn_s_barrier();
        asm volatile("s_waitcnt lgkmcnt(0)" ::: "memory");
        __builtin_amdgcn_sched_barrier(0);
        __builtin_amdgcn_s_setprio(1);
#pragma unroll
        for (int ks = 0; ks < 2; ks++)
#pragma unroll
            for (int m = 0; m < 4; m++)
#pragma unroll
                for (int n = 0; n < 2; n++)
                    acc[4 + m][2 + n] = __builtin_amdgcn_mfma_i32_16x16x64_i8(a[m][ks], b1[n][ks], acc[4 + m][2 + n], 0, 0, 0);
        __builtin_amdgcn_s_setprio(0);
        __builtin_amdgcn_s_barrier();

        // ===== ph4: stage A-h0+B-h1(T+2); vmcnt(6); MFMA q(1,0) (regs only) =====
        stageA(0, T + 2, kT2);
        stageB(1, T + 2, kT2);
        asm volatile("s_waitcnt vmcnt(6)" ::: "memory");  // retires all of tile T+1
        __builtin_amdgcn_s_barrier();
        __builtin_amdgcn_s_setprio(1);
#pragma unroll
        for (int ks = 0; ks < 2; ks++)
#pragma unroll
            for (int m = 0; m < 4; m++)
#pragma unroll
                for (int n = 0; n < 2; n++)
                    acc[4 + m][n] = __builtin_amdgcn_mfma_i32_16x16x64_i8(a[m][ks], b0[n][ks], acc[4 + m][n], 0, 0, 0);
        __builtin_amdgcn_s_setprio(0);
        __builtin_amdgcn_s_barrier();
    }

    // ---- epilogue: y = acc * (a_scale * w_scale[col]) + bias[col] ----
    float a_s = fmaxf(__uint_as_float(*amax) / QMAX_F, EPS_F);
    const int row0 = bm * BM + wr * 128 + (kg << 2);
    const int col0 = bn * BN + wc * 64 + rA;
#pragma unroll
    for (int n = 0; n < 4; n++) {
        int col = col0 + n * 16;
        float f = a_s * w_scale[col];
        float bv = bias[col];
#pragma unroll
        for (int m = 0; m < 8; m++) {
            size_t base = (size_t)(row0 + m * 16) * N + col;
#pragma unroll
            for (int j = 0; j < 4; j++)
                out[base + (size_t)j * N] = (float)acc[m][n][j] * f + bv;
        }
    }
}

extern "C" void kernel_launch(void* const* d_in, const int* in_sizes, int n_in,
                              void* d_out, int out_size, void* d_ws, size_t ws_size,
                              hipStream_t stream) {
    const float* x = (const float*)d_in[0];
    const float* w = (const float*)d_in[1];
    const float* bias = (const float*)d_in[2];
    float* out = (float*)d_out;

    const int N = in_sizes[2];      // 4096
    const int K = in_sizes[1] / N;  // 4096
    const int M = in_sizes[0] / K;  // 16384

    char* ws = (char*)d_ws;
    unsigned* amax = (unsigned*)ws;
    float* w_scale = (float*)(ws + WSCALE_OFF);
    char* xq = ws + XQ_OFF;
    char* wq = ws + XQ_OFF + (size_t)M * K;

    size_t needed = XQ_OFF + (size_t)M * K + (size_t)N * K;
    if (ws_size < needed) return;

    hipMemsetAsync(amax, 0, 4, stream);

    int n4x = (M * K) / 4;
    absmax_kernel<<<2048, 256, 0, stream>>>((const float4*)x, amax, n4x);
    quantx_kernel<<<2048, 256, 0, stream>>>((const float4*)x, amax, (int*)xq, n4x);
    quantw_kernel<<<N, 256, 0, stream>>>((const float4*)w, (int*)wq, w_scale, K / 4);

    int grid = (M / BM) * (N / BN);  // 64*16 = 1024
    gemm_i8_8ph<<<grid, 512, 0, stream>>>(xq, wq, w_scale, amax, bias, out, M, N, K);
}